// Round 6
// baseline (145.711 us; speedup 1.0000x reference)
//
#include <hip/hip_runtime.h>
#include <hip/hip_bf16.h>
#include <math.h>

// ---------------------------------------------------------------------------
// MLPConv4d via bf16 MFMA implicit GEMM (v4: double-buffered, 1 barrier/ci).
// conv1: x[16][32^4] fp32 -> hpad[64][18^4] bf16 (GELU'd, zero shell)
// conv2: hpad -> out[16][8^4] fp32 (split-K atomics onto bias-init'd out)
// K layout: k' = grp*4 + k4 (grp<27; k4=3 slot and k'>=108 are zero WEIGHTS).
// B-tile LDS [64 sp][136 k'] bf16, phys byte = logical ^ (((sp>>3)&7)<<4).
// Footprint sF [i1 5][i2 5][i3 5][i4 18] shorts.
// Pipeline (iter ci, ONE barrier at end):
//   stage fp(ci+2)->sF[ci&1] | prefetch x(ci+3) | expand sF[(ci+1)&1]->sB[(ci+1)&1]
//   | MFMA(ci): sB[ci&1] x A(ci) | issue A(ci+2)   -- all phases disjoint bufs.
// ---------------------------------------------------------------------------

typedef __attribute__((ext_vector_type(8))) short short8;
typedef __attribute__((ext_vector_type(4))) float f32x4;
typedef __attribute__((ext_vector_type(4))) unsigned int uint4v;

__device__ __forceinline__ unsigned short f2bf(float v) {
    __hip_bfloat16 b = __float2bfloat16(v);
    return *(unsigned short*)&b;
}

// ---- fused setup: prepack w1/w2 (zero-padded k'), bias-init out, zero hpad -
__global__ void setup_kernel(const float* __restrict__ w1, const float* __restrict__ w2,
                             const float* __restrict__ b2,
                             unsigned short* __restrict__ w1p, unsigned short* __restrict__ w2p,
                             uint4v* __restrict__ hz, float* __restrict__ out) {
    int b = blockIdx.x, tid = threadIdx.x;
    if (b < 544) {                       // w1p: 16*64*136 = 139264 = 544*256
        int i = b * 256 + tid;
        int kp = i % 136, co = (i / 136) & 63, ci = i / 8704;
        float v = 0.f;
        if (kp < 108 && (kp & 3) < 3) v = w1[(co * 16 + ci) * 81 + (kp >> 2) * 3 + (kp & 3)];
        w1p[i] = f2bf(v);
    } else if (b < 1088) {               // w2p: 64*16*136 = 139264
        int i = (b - 544) * 256 + tid;
        int kp = i % 136, co = (i / 136) & 15, ci = i / 2176;
        float v = 0.f;
        if (kp < 108 && (kp & 3) < 3) v = w2[(co * 64 + ci) * 81 + (kp >> 2) * 3 + (kp & 3)];
        w2p[i] = f2bf(v);
    } else if (b < 1344) {               // out = bias: 65536
        int i = (b - 1088) * 256 + tid;
        out[i] = b2[i >> 12];
    } else {                             // zero hpad: 839808 uint4
        int i = (b - 1344) * 256 + tid;  // 2752*256 = 704512
        hz[i] = (uint4v){0, 0, 0, 0};
        int j = i + 704512;
        if (j < 839808) hz[j] = (uint4v){0, 0, 0, 0};
    }
}

// ---------------- conv1: MFMA + GELU, 64-sp tiles, dbuf pipeline ------------
// Block: sp 64 = (o1,o2,o3,o4)=(2,2,2,8), 64 co. Grid 1024 (3 blocks/CU).
// Wave wv: sp-tiles 2(wv>>1)+{0,1}, co-tiles 2(wv&1)+{0,1}; 16 MFMA/ci.
__global__ __launch_bounds__(256, 3) void conv1_mfma(
        const float* __restrict__ x, const unsigned short* __restrict__ w1p,
        const float* __restrict__ b1, unsigned short* __restrict__ hpad) {
    __shared__ unsigned short sF[2][2250];   // 2 x 4500 B
    __shared__ unsigned short sB[2][8704];   // 2 x 17408 B

    const int tid = threadIdx.x;
    const int bid = blockIdx.x;
    const int t4 = bid & 1, t3 = (bid >> 1) & 7, t2 = (bid >> 4) & 7, t1 = bid >> 7;
    const int bo1 = 2 * t1, bo2 = 2 * t2, bo3 = 2 * t3, bo4 = 8 * t4;
    const int g1b = 2 * bo1 - 1, g2b = 2 * bo2 - 1, g3b = 2 * bo3 - 1, g4b = 2 * bo4 - 1;

    // ---- staging slots: 1125 units (2 i4-elems each), u = tid + 256r, r<5 --
    int offs[5], swb[5];
    unsigned char mka = 0, mkb = 0;
#pragma unroll
    for (int r = 0; r < 5; ++r) {
        int u = tid + 256 * r;
        bool uok = u < 1125;
        int uu = uok ? u : 0;
        int p = uu % 9, q = uu / 9;
        int i3 = q % 5; q /= 5;
        int i2 = q % 5; int i1 = q / 5;
        int g1 = g1b + i1, g2 = g2b + i2, g3 = g3b + i3;
        bool ok123 = uok & ((unsigned)g1 < 32u) & ((unsigned)g2 < 32u) & ((unsigned)g3 < 32u);
        int g4a = g4b + 2 * p;
        offs[r] = ((g1 * 32 + g2) * 32 + g3) * 32 + g4a;
        if (ok123 && (unsigned)g4a < 32u) mka |= 1 << r;
        if (ok123 && (unsigned)(g4a + 1) < 32u) mkb |= 1 << r;
        swb[r] = 2 * (((i1 * 5 + i2) * 5 + i3) * 18 + 2 * p);
    }

    // ---- expand constants ----
    const int sp = tid & 63, g0 = tid >> 6;
    const int o4l = sp & 7, o3l = (sp >> 3) & 1, o2l = (sp >> 4) & 1, o1l = sp >> 5;
    const int fpbase = o1l * 900 + o2l * 180 + o3l * 36 + o4l * 2;   // shorts
    const int wkey = ((sp >> 3) & 7) << 4;
    const int wbase = sp * 272;

    int rba[4], rbb[4], wba[4];
#pragma unroll
    for (int i = 0; i < 4; ++i) {
        int gp = g0 + 4 * i;
        int ga = 2 * gp, gb = 2 * gp + 1;
        if (ga > 26) ga = 26;
        if (gb > 26) gb = 26;                 // aliases killed by zero weights
        rba[i] = 2 * (fpbase + (ga / 9) * 450 + ((ga / 3) % 3) * 90 + (ga % 3) * 18);
        rbb[i] = 2 * (fpbase + (gb / 9) * 450 + ((gb / 3) % 3) * 90 + (gb % 3) * 18);
        wba[i] = (wbase + gp * 16) ^ wkey;
    }
    const bool zlast = (g0 >= 2);             // i==3 -> gp>=14: zero k' 112..127

    // ---- mfma constants ----
    const int lane = tid & 63, wv = tid >> 6;
    const int n16 = lane & 15, hi = lane >> 4, n8 = n16 >> 3;
    const int bbase = n16 * 272 + hi * 16;
    const int ct0 = 2 * (wv & 1);
    const int st0 = 2 * (wv >> 1);

    // ---- helpers ----
    auto gather = [&](int ci, unsigned (&dst)[5]) {
        const float* xc = x + (size_t)ci * 1048576;
#pragma unroll
        for (int r = 0; r < 5; ++r) {
            float va = 0.f, vb = 0.f;
            if ((mka >> r) & 1) va = xc[offs[r]];
            if ((mkb >> r) & 1) vb = xc[offs[r] + 1];
            dst[r] = (unsigned)f2bf(va) | ((unsigned)f2bf(vb) << 16);
        }
    };
    auto stageTo = [&](int buf, const unsigned (&src)[5]) {
        char* sfw = (char*)sF[buf];
#pragma unroll
        for (int r = 0; r < 4; ++r) *(unsigned*)(sfw + swb[r]) = src[r];
        if (tid < 101) *(unsigned*)(sfw + swb[4]) = src[4];
    };
    auto expand = [&](int buf) {
        const char* sfr = (const char*)sF[buf];
        char* sbw = (char*)sB[buf];
#pragma unroll
        for (int i = 0; i < 4; ++i) {
            if (i == 3 && zlast) {
                *(uint4v*)(sbw + wba[3]) = (uint4v){0, 0, 0, 0};
            } else {
                unsigned w0  = *(const unsigned*)(sfr + rba[i]);
                unsigned w1_ = *(const unsigned*)(sfr + rba[i] + 4);
                unsigned w2_ = *(const unsigned*)(sfr + rbb[i]);
                unsigned w3_ = *(const unsigned*)(sfr + rbb[i] + 4);
                *(uint4v*)(sbw + wba[i]) = (uint4v){w0, w1_, w2_, w3_};
            }
        }
    };
    auto loadA = [&](int ci, short8 (&Ac)[8]) {
        const unsigned short* aw0 = w1p + (size_t)(ci * 64 + 16 * ct0 + n16) * 136 + hi * 8;
#pragma unroll
        for (int k = 0; k < 4; ++k) Ac[k] = *(const short8*)(aw0 + 32 * k);
        const unsigned short* aw1 = aw0 + 16 * 136;
#pragma unroll
        for (int k = 0; k < 4; ++k) Ac[4 + k] = *(const short8*)(aw1 + 32 * k);
    };

    f32x4 acc[2][2];
#pragma unroll
    for (int c = 0; c < 2; ++c)
#pragma unroll
    for (int t = 0; t < 2; ++t) acc[c][t] = (f32x4){0.f, 0.f, 0.f, 0.f};

    short8 A0[8], A1[8];
    unsigned fvp[5], nfp[5];

    // ---- prologue: fp(0)->sF[0], fp(1)->sF[1]; expand B(0); A(0),A(1),fp(2) --
    {
        unsigned t0[5], t1r[5];
        gather(0, t0);
        stageTo(0, t0);
        gather(1, t1r);
        stageTo(1, t1r);
    }
    __syncthreads();
    expand(0);
    loadA(0, A0);
    loadA(1, A1);
    gather(2, fvp);
    __syncthreads();

    // ---- main loop: iter ci, one barrier each ----
    auto body = [&](int ci, short8 (&Ac)[8]) {
        // 1. stage fp(ci+2) -> sF[ci&1]
        if (ci <= 13) stageTo(ci & 1, fvp);
        // 2. prefetch fp(ci+3)
        if (ci <= 12) gather(ci + 3, nfp);
        // 3. expand fp(ci+1): sF[(ci+1)&1] -> sB[(ci+1)&1]
        if (ci <= 14) expand((ci + 1) & 1);
        // 4. MFMA(ci): sB[ci&1] x A(ci)
        {
            const char* sbr = (const char*)sB[ci & 1];
#pragma unroll
            for (int tt = 0; tt < 2; ++tt) {
                const int t = st0 + tt;
                const int tb = bbase + t * 4352;
                const int xv = (((2 * t) & 7) + n8) << 4;
                short8 b0  = *(const short8*)(sbr + ((tb + 0)   ^ xv));
                short8 b1f = *(const short8*)(sbr + ((tb + 64)  ^ xv));
                short8 b2f = *(const short8*)(sbr + ((tb + 128) ^ xv));
                short8 b3f = *(const short8*)(sbr + ((tb + 192) ^ xv));
                acc[0][tt] = __builtin_amdgcn_mfma_f32_16x16x32_bf16(Ac[0], b0,  acc[0][tt], 0, 0, 0);
                acc[0][tt] = __builtin_amdgcn_mfma_f32_16x16x32_bf16(Ac[1], b1f, acc[0][tt], 0, 0, 0);
                acc[0][tt] = __builtin_amdgcn_mfma_f32_16x16x32_bf16(Ac[2], b2f, acc[0][tt], 0, 0, 0);
                acc[0][tt] = __builtin_amdgcn_mfma_f32_16x16x32_bf16(Ac[3], b3f, acc[0][tt], 0, 0, 0);
                acc[1][tt] = __builtin_amdgcn_mfma_f32_16x16x32_bf16(Ac[4], b0,  acc[1][tt], 0, 0, 0);
                acc[1][tt] = __builtin_amdgcn_mfma_f32_16x16x32_bf16(Ac[5], b1f, acc[1][tt], 0, 0, 0);
                acc[1][tt] = __builtin_amdgcn_mfma_f32_16x16x32_bf16(Ac[6], b2f, acc[1][tt], 0, 0, 0);
                acc[1][tt] = __builtin_amdgcn_mfma_f32_16x16x32_bf16(Ac[7], b3f, acc[1][tt], 0, 0, 0);
            }
        }
        // 5. issue A(ci+2) into Ac (WAR after MFMA reads; 2 iters to land)
        if (ci <= 13) loadA(ci + 2, Ac);
        // 6. fv = nf
        if (ci <= 12) {
#pragma unroll
            for (int r = 0; r < 5; ++r) fvp[r] = nfp[r];
        }
    };

    for (int cc = 0; cc < 16; cc += 2) {
        body(cc, A0);
        __syncthreads();
        body(cc + 1, A1);
        __syncthreads();
    }

    // ---- epilogue: bias + exact GELU + bf16 store ----
#pragma unroll
    for (int c = 0; c < 2; ++c) {
#pragma unroll
        for (int tt = 0; tt < 2; ++tt) {
            int spl = 16 * (st0 + tt) + n16;
            int e4 = spl & 7, e3 = (spl >> 3) & 1, e2 = (spl >> 4) & 1, e1 = spl >> 5;
            size_t base = (size_t)(bo1 + e1 + 1) * 5832 + (bo2 + e2 + 1) * 324 +
                          (bo3 + e3 + 1) * 18 + (bo4 + e4 + 1);
#pragma unroll
            for (int r = 0; r < 4; ++r) {
                int co = 16 * (ct0 + c) + 4 * hi + r;
                float v = acc[c][tt][r] + b1[co];
                v = 0.5f * v * (1.f + erff(v * 0.70710678118654752f));
                hpad[(size_t)co * 104976 + base] = f2bf(v);
            }
        }
    }
}

// ---------------- conv2: MFMA split-K, 64-sp tiles --------------------------
// Block: sp 64 = (2,2,2,8) over out 8^4 (64 tiles) x 16 ci-groups (4 ci).
// Grid 1024. Wave wv: sp-tile wv, all 16 co; 4 MFMA/ci.
__global__ __launch_bounds__(256, 4) void conv2_mfma(
        const unsigned short* __restrict__ hpad, const unsigned short* __restrict__ w2p,
        float* __restrict__ out) {
    __shared__ unsigned short sF[2250];
    __shared__ unsigned short sB[8704];

    const int tid = threadIdx.x;
    const int bid = blockIdx.x;
    const int s = bid & 63, cig = bid >> 6;
    const int t3 = s & 3, t2 = (s >> 2) & 3, t1 = s >> 4;
    const int bo1 = 2 * t1, bo2 = 2 * t2, bo3 = 2 * t3;   // bo4 = 0

    // staging: hpad zero-padded -> no masks; direct u32 loads
    int offs[5], swb[5];
#pragma unroll
    for (int r = 0; r < 5; ++r) {
        int u = tid + 256 * r;
        if (u >= 1125) u = 0;
        int p = u % 9, q = u / 9;
        int i3 = q % 5; q /= 5;
        int i2 = q % 5; int i1 = q / 5;
        offs[r] = (2 * bo1 + i1) * 5832 + (2 * bo2 + i2) * 324 + (2 * bo3 + i3) * 18 + 2 * p;
        swb[r] = 2 * (((i1 * 5 + i2) * 5 + i3) * 18 + 2 * p);
    }

    const int sp = tid & 63, g0 = tid >> 6;
    const int o4l = sp & 7, o3l = (sp >> 3) & 1, o2l = (sp >> 4) & 1, o1l = sp >> 5;
    const int fpbase = o1l * 900 + o2l * 180 + o3l * 36 + o4l * 2;
    const int wkey = ((sp >> 3) & 7) << 4;
    const int wbase = sp * 272;

    int rba[4], rbb[4], wba[4];
#pragma unroll
    for (int i = 0; i < 4; ++i) {
        int gp = g0 + 4 * i;
        int ga = 2 * gp, gb = 2 * gp + 1;
        if (ga > 26) ga = 26;
        if (gb > 26) gb = 26;
        rba[i] = 2 * (fpbase + (ga / 9) * 450 + ((ga / 3) % 3) * 90 + (ga % 3) * 18);
        rbb[i] = 2 * (fpbase + (gb / 9) * 450 + ((gb / 3) % 3) * 90 + (gb % 3) * 18);
        wba[i] = (wbase + gp * 16) ^ wkey;
    }
    const bool zlast = (g0 >= 2);

    const int lane = tid & 63, wv = tid >> 6;
    const int n16 = lane & 15, hi = lane >> 4, n8 = n16 >> 3;
    const int bbase = n16 * 272 + hi * 16;

    unsigned fvp[5];
    {
        const unsigned short* hc = hpad + (size_t)(cig * 4) * 104976;
#pragma unroll
        for (int r = 0; r < 5; ++r) fvp[r] = *(const unsigned*)(hc + offs[r]);
    }

    f32x4 acc = (f32x4){0.f, 0.f, 0.f, 0.f};

    for (int s8 = 0; s8 < 4; ++s8) {
        const int ci = cig * 4 + s8;
#pragma unroll
        for (int r = 0; r < 4; ++r) *(unsigned*)((char*)sF + swb[r]) = fvp[r];
        if (tid < 101) *(unsigned*)((char*)sF + swb[4]) = fvp[4];
        __syncthreads();   // B1

        const unsigned short* aw = w2p + (size_t)(ci * 16 + n16) * 136 + hi * 8;
        short8 a0 = *(const short8*)(aw);
        short8 a1 = *(const short8*)(aw + 32);
        short8 a2 = *(const short8*)(aw + 64);
        short8 a3 = *(const short8*)(aw + 96);

        unsigned nfp[5];
        if (s8 < 3) {
            const unsigned short* hc = hpad + (size_t)(ci + 1) * 104976;
#pragma unroll
            for (int r = 0; r < 5; ++r) nfp[r] = *(const unsigned*)(hc + offs[r]);
        }

#pragma unroll
        for (int i = 0; i < 4; ++i) {
            if (i == 3 && zlast) {
                *(uint4v*)((char*)sB + wba[3]) = (uint4v){0, 0, 0, 0};
            } else {
                unsigned w0  = *(const unsigned*)((const char*)sF + rba[i]);
                unsigned w1_ = *(const unsigned*)((const char*)sF + rba[i] + 4);
                unsigned w2_ = *(const unsigned*)((const char*)sF + rbb[i]);
                unsigned w3_ = *(const unsigned*)((const char*)sF + rbb[i] + 4);
                *(uint4v*)((char*)sB + wba[i]) = (uint4v){w0, w1_, w2_, w3_};
            }
        }
        __syncthreads();   // B2

        {
            const int tb = bbase + wv * 4352;
            const int xv = (((2 * wv) & 7) + n8) << 4;
            short8 b0  = *(const short8*)((const char*)sB + ((tb + 0)   ^ xv));
            short8 b1f = *(const short8*)((const char*)sB + ((tb + 64)  ^ xv));
            short8 b2f = *(const short8*)((const char*)sB + ((tb + 128) ^ xv));
            short8 b3f = *(const short8*)((const char*)sB + ((tb + 192) ^ xv));
            acc = __builtin_amdgcn_mfma_f32_16x16x32_bf16(a0, b0,  acc, 0, 0, 0);
            acc = __builtin_amdgcn_mfma_f32_16x16x32_bf16(a1, b1f, acc, 0, 0, 0);
            acc = __builtin_amdgcn_mfma_f32_16x16x32_bf16(a2, b2f, acc, 0, 0, 0);
            acc = __builtin_amdgcn_mfma_f32_16x16x32_bf16(a3, b3f, acc, 0, 0, 0);
        }

        if (s8 < 3) {
#pragma unroll
            for (int r = 0; r < 5; ++r) fvp[r] = nfp[r];
        }
    }

    {
        int spl = 16 * wv + n16;
        int e4 = spl & 7, e3 = (spl >> 3) & 1, e2 = (spl >> 4) & 1, e1 = spl >> 5;
        int o1 = bo1 + e1, o2 = bo2 + e2, o3 = bo3 + e3, o4 = e4;
#pragma unroll
        for (int r = 0; r < 4; ++r) {
            int co = 4 * hi + r;
            atomicAdd(&out[(size_t)co * 4096 + o1 * 512 + o2 * 64 + o3 * 8 + o4], acc[r]);
        }
    }
}

// ---------------------------------------------------------------------------
extern "C" void kernel_launch(void* const* d_in, const int* in_sizes, int n_in,
                              void* d_out, int out_size, void* d_ws, size_t ws_size,
                              hipStream_t stream) {
    const float* x  = (const float*)d_in[0];
    const float* w1 = (const float*)d_in[1];
    const float* b1 = (const float*)d_in[2];
    const float* w2 = (const float*)d_in[3];
    const float* b2 = (const float*)d_in[4];
    float* out = (float*)d_out;

    unsigned short* hpad = (unsigned short*)d_ws;        // 64*18^4 = 6,718,464 bf16
    unsigned short* w1p  = hpad + 6718464;               // 139,264 bf16
    unsigned short* w2p  = w1p + 139264;                 // 139,264 bf16

    setup_kernel<<<4096, 256, 0, stream>>>(w1, w2, b2, w1p, w2p, (uint4v*)hpad, out);
    conv1_mfma<<<1024, 256, 0, stream>>>(x, w1p, b1, hpad);
    conv2_mfma<<<1024, 256, 0, stream>>>(hpad, w2p, out);
}

// Round 7
// 138.846 us; speedup vs baseline: 1.0494x; 1.0494x over previous
//
#include <hip/hip_runtime.h>
#include <hip/hip_bf16.h>
#include <math.h>

// ---------------------------------------------------------------------------
// MLPConv4d via bf16 MFMA implicit GEMM (v5: r4 geometry + lgkm-only barriers).
// conv1: x[16][32^4] fp32 -> hpad[64][18^4] bf16 (GELU'd, zero shell)
// conv2: hpad -> out[16][8^4] fp32 (split-K atomics onto bias-init'd out)
// K layout: k' = grp*4 + k4 (grp<27; k4=3 slot and k'>=108 are zero WEIGHTS).
// B-tile LDS [128 sp][136 k'] bf16, phys byte = logical ^ (((sp>>3)&7)<<4).
// Barriers: s_waitcnt lgkmcnt(0) + raw s_barrier ONLY -> global loads stay in
// flight across barriers (T4); compiler inserts vmcnt waits at register use.
// ---------------------------------------------------------------------------

typedef __attribute__((ext_vector_type(8))) short short8;
typedef __attribute__((ext_vector_type(4))) float f32x4;
typedef __attribute__((ext_vector_type(4))) unsigned int uint4v;

__device__ __forceinline__ unsigned short f2bf(float v) {
    __hip_bfloat16 b = __float2bfloat16(v);
    return *(unsigned short*)&b;
}

__device__ __forceinline__ void lgkm_barrier() {
    asm volatile("s_waitcnt lgkmcnt(0)" ::: "memory");
    __builtin_amdgcn_s_barrier();
}

// ---- fused setup: prepack w1/w2 (zero-padded k'), bias-init out, zero hpad -
__global__ void setup_kernel(const float* __restrict__ w1, const float* __restrict__ w2,
                             const float* __restrict__ b2,
                             unsigned short* __restrict__ w1p, unsigned short* __restrict__ w2p,
                             uint4v* __restrict__ hz, float* __restrict__ out) {
    int b = blockIdx.x, tid = threadIdx.x;
    if (b < 544) {                       // w1p: 16*64*136 = 139264 = 544*256
        int i = b * 256 + tid;
        int kp = i % 136, co = (i / 136) & 63, ci = i / 8704;
        float v = 0.f;
        if (kp < 108 && (kp & 3) < 3) v = w1[(co * 16 + ci) * 81 + (kp >> 2) * 3 + (kp & 3)];
        w1p[i] = f2bf(v);
    } else if (b < 1088) {               // w2p: 64*16*136 = 139264
        int i = (b - 544) * 256 + tid;
        int kp = i % 136, co = (i / 136) & 15, ci = i / 2176;
        float v = 0.f;
        if (kp < 108 && (kp & 3) < 3) v = w2[(co * 64 + ci) * 81 + (kp >> 2) * 3 + (kp & 3)];
        w2p[i] = f2bf(v);
    } else if (b < 1344) {               // out = bias: 65536
        int i = (b - 1088) * 256 + tid;
        out[i] = b2[i >> 12];
    } else {                             // zero hpad: 839808 uint4
        int i = (b - 1344) * 256 + tid;  // 2752*256 = 704512
        hz[i] = (uint4v){0, 0, 0, 0};
        int j = i + 704512;
        if (j < 839808) hz[j] = (uint4v){0, 0, 0, 0};
    }
}

// ---------------- conv1: MFMA + GELU, 128-sp tiles, lgkm barriers -----------
// Block: sp 128 = (o1,o2,o3,o4)=(2,2,4,8), 64 co. Grid 512, 256 thr.
// Wave wv: co-tiles 2(wv&1)+{0,1}, sp-tiles (wv>>1)*4..+3; 32 MFMA/ci.
// Per ci: stage(regs->sF) B1 [issue x(ci+2) | expand sF->sB] B2 [MFMA | issue A(ci+2)]
__global__ __launch_bounds__(256) void conv1_mfma(
        const float* __restrict__ x, const unsigned short* __restrict__ w1p,
        const float* __restrict__ b1, unsigned short* __restrict__ hpad) {
    __shared__ unsigned short sF[4050];    // footprint [5][5][9][18]
    __shared__ unsigned short sB[17408];   // B tile 128x136

    const int tid = threadIdx.x;
    const int bid = blockIdx.x;
    const int t4 = bid & 1, t3 = (bid >> 1) & 3, t2 = (bid >> 3) & 7, t1 = bid >> 6;
    const int bo1 = 2 * t1, bo2 = 2 * t2, bo3 = 4 * t3, bo4 = 8 * t4;
    const int g1b = 2 * bo1 - 1, g2b = 2 * bo2 - 1, g3b = 2 * bo3 - 1, g4b = 2 * bo4 - 1;

    // one-time LDS zeros (consumed after first barriers)
    if (tid < 225) sF[tid * 18 + 17] = 0;                     // pad column
    {
        int sp_ = tid & 127, g0_ = tid >> 7;
        int K_ = ((sp_ >> 3) & 7) << 4;
        *(uint4v*)((char*)sB + ((sp_ * 272 + (14 + g0_) * 16) ^ K_)) = (uint4v){0, 0, 0, 0};
    }

    // ---- staging slots (precomputed once): e = tid + 256*r, e < 3825 ----
    int off[15], lidx[15];
    unsigned vmask = 0;
#pragma unroll
    for (int r = 0; r < 15; ++r) {
        int e = tid + 256 * r;
        int ee = e < 3825 ? e : 0;
        int i4 = ee % 17; int q = ee / 17;
        int i3 = q % 9; q /= 9;
        int i2 = q % 5; int i1 = q / 5;
        int g1 = g1b + i1, g2 = g2b + i2, g3 = g3b + i3, g4 = g4b + i4;
        bool ok = (e < 3825) & ((unsigned)g1 < 32u) & ((unsigned)g2 < 32u) &
                  ((unsigned)g3 < 32u) & ((unsigned)g4 < 32u);
        if (ok) vmask |= (1u << r);
        off[r] = ok ? ((g1 * 32 + g2) * 32 + g3) * 32 + g4 : 0;
        lidx[r] = i1 * 810 + i2 * 162 + i3 * 18 + i4;
    }

    // ---- expand constants ----
    const int sp = tid & 127, g0 = tid >> 7;
    const int o4l = sp & 7, o3l = (sp >> 3) & 3, o2l = (sp >> 5) & 1, o1l = sp >> 6;
    const int fpbase = o1l * 1620 + o2l * 324 + o3l * 36 + o4l * 2;
    const int wkey = ((sp >> 3) & 7) << 4;
    const int wbase = sp * 272;

    int rba[7], rbb[7], wba[7];
#pragma unroll
    for (int i = 0; i < 7; ++i) {
        int gp = g0 + 2 * i;
        int ga = 2 * gp, gb = 2 * gp + 1;
        if (gb > 26) gb = 26;                 // alias; killed by zero weights
        rba[i] = 2 * (fpbase + (ga / 9) * 810 + ((ga / 3) % 3) * 162 + (ga % 3) * 18);
        rbb[i] = 2 * (fpbase + (gb / 9) * 810 + ((gb / 3) % 3) * 162 + (gb % 3) * 18);
        wba[i] = (wbase + gp * 16) ^ wkey;
    }

    // ---- mfma constants ----
    const int lane = tid & 63, wv = tid >> 6;
    const int n16 = lane & 15, hi = lane >> 4, n8 = n16 >> 3;
    const int bbase = n16 * 272 + hi * 16;
    const int c0 = 2 * (wv & 1);          // co-tiles c0, c0+1 (16 co each)
    const int shalf = (wv >> 1) * 4;      // sp-tiles shalf .. shalf+3

    // ---- helpers ----
    auto issueX = [&](int ci, float (&dst)[15]) {
        const float* xc = x + (size_t)ci * 1048576;
#pragma unroll
        for (int r = 0; r < 15; ++r) dst[r] = xc[off[r]];
    };
    auto stage = [&](const float (&src)[15]) {
#pragma unroll
        for (int r = 0; r < 14; ++r) {
            float v = ((vmask >> r) & 1) ? src[r] : 0.f;
            sF[lidx[r]] = f2bf(v);
        }
        if (tid < 241) {
            float v = ((vmask >> 14) & 1) ? src[14] : 0.f;
            sF[lidx[14]] = f2bf(v);
        }
    };
    auto loadA = [&](int ci, short8 (&Ac)[8]) {
        const unsigned short* aw0 = w1p + (size_t)(ci * 64 + 16 * c0 + n16) * 136 + hi * 8;
#pragma unroll
        for (int k = 0; k < 4; ++k) Ac[k] = *(const short8*)(aw0 + 32 * k);
        const unsigned short* aw1 = aw0 + 16 * 136;
#pragma unroll
        for (int k = 0; k < 4; ++k) Ac[4 + k] = *(const short8*)(aw1 + 32 * k);
    };

    f32x4 acc[2][4];
#pragma unroll
    for (int c = 0; c < 2; ++c)
#pragma unroll
    for (int t = 0; t < 4; ++t) acc[c][t] = (f32x4){0.f, 0.f, 0.f, 0.f};

    float fvA[15], fvB[15];
    short8 A0[8], A1[8];

    // ---- prologue: issue x(0),x(1) and A(0),A(1) ----
    issueX(0, fvA);
    issueX(1, fvB);
    loadA(0, A0);
    loadA(1, A1);

    auto body = [&](int ci, short8 (&Ac)[8], float (&fvC)[15]) {
        // 1. stage (mask + f2bf deferred to here; vmcnt wait lands here, 2 iters late)
        stage(fvC);
        lgkm_barrier();                        // B1: sF ready, sB free
        // 2. refill this float buffer for ci+2 (issued, not waited)
        if (ci <= 13) issueX(ci + 2, fvC);
        // 3. expand im2col: sF -> sB (swizzled b128 writes)
#pragma unroll
        for (int i = 0; i < 7; ++i) {
            unsigned w0  = *(const unsigned*)((const char*)sF + rba[i]);
            unsigned w1_ = *(const unsigned*)((const char*)sF + rba[i] + 4);
            unsigned w2_ = *(const unsigned*)((const char*)sF + rbb[i]);
            unsigned w3_ = *(const unsigned*)((const char*)sF + rbb[i] + 4);
            *(uint4v*)((char*)sB + wba[i]) = (uint4v){w0, w1_, w2_, w3_};
        }
        lgkm_barrier();                        // B2: sB ready
        // 4. MFMA: 4 sp-tiles x 2 co-tiles x 4 K-steps
#pragma unroll
        for (int tt = 0; tt < 4; ++tt) {
            const int t = shalf + tt;
            const int tb = bbase + t * 4352;
            const int xv = (((2 * t) & 7) + n8) << 4;
            short8 b0  = *(const short8*)((const char*)sB + ((tb + 0)   ^ xv));
            short8 b1f = *(const short8*)((const char*)sB + ((tb + 64)  ^ xv));
            short8 b2f = *(const short8*)((const char*)sB + ((tb + 128) ^ xv));
            short8 b3f = *(const short8*)((const char*)sB + ((tb + 192) ^ xv));
            acc[0][tt] = __builtin_amdgcn_mfma_f32_16x16x32_bf16(Ac[0], b0,  acc[0][tt], 0, 0, 0);
            acc[0][tt] = __builtin_amdgcn_mfma_f32_16x16x32_bf16(Ac[1], b1f, acc[0][tt], 0, 0, 0);
            acc[0][tt] = __builtin_amdgcn_mfma_f32_16x16x32_bf16(Ac[2], b2f, acc[0][tt], 0, 0, 0);
            acc[0][tt] = __builtin_amdgcn_mfma_f32_16x16x32_bf16(Ac[3], b3f, acc[0][tt], 0, 0, 0);
            acc[1][tt] = __builtin_amdgcn_mfma_f32_16x16x32_bf16(Ac[4], b0,  acc[1][tt], 0, 0, 0);
            acc[1][tt] = __builtin_amdgcn_mfma_f32_16x16x32_bf16(Ac[5], b1f, acc[1][tt], 0, 0, 0);
            acc[1][tt] = __builtin_amdgcn_mfma_f32_16x16x32_bf16(Ac[6], b2f, acc[1][tt], 0, 0, 0);
            acc[1][tt] = __builtin_amdgcn_mfma_f32_16x16x32_bf16(Ac[7], b3f, acc[1][tt], 0, 0, 0);
        }
        // 5. refill A regs for ci+2 (WAR after MFMA reads; 2 phases to land)
        if (ci <= 13) loadA(ci + 2, Ac);
    };

    for (int cc = 0; cc < 16; cc += 2) {
        body(cc, A0, fvA);
        body(cc + 1, A1, fvB);
    }

    // ---- epilogue: bias + exact GELU + bf16 store into padded h ----
#pragma unroll
    for (int c = 0; c < 2; ++c) {
        float bv[4];
#pragma unroll
        for (int r = 0; r < 4; ++r) bv[r] = b1[16 * (c0 + c) + hi * 4 + r];
#pragma unroll
        for (int tt = 0; tt < 4; ++tt) {
            int spl = 16 * (shalf + tt) + n16;
            int e4 = spl & 7, e3 = (spl >> 3) & 3, e2 = (spl >> 5) & 1, e1 = spl >> 6;
            size_t base = (size_t)(bo1 + e1 + 1) * 5832 + (bo2 + e2 + 1) * 324 +
                          (bo3 + e3 + 1) * 18 + (bo4 + e4 + 1);
#pragma unroll
            for (int r = 0; r < 4; ++r) {
                int co = 16 * (c0 + c) + 4 * hi + r;
                float v = acc[c][tt][r] + bv[r];
                v = 0.5f * v * (1.f + erff(v * 0.70710678118654752f));
                hpad[(size_t)co * 104976 + base] = f2bf(v);
            }
        }
    }
}

// ---------------- conv2: MFMA split-K, 64-sp tiles, lgkm barriers -----------
// Block: sp 64 = (2,2,2,8) over out 8^4 (64 tiles) x 16 ci-groups (4 ci).
// Grid 1024. Wave wv: sp-tile wv, all 16 co; 4 MFMA/ci.
__global__ __launch_bounds__(256, 4) void conv2_mfma(
        const unsigned short* __restrict__ hpad, const unsigned short* __restrict__ w2p,
        float* __restrict__ out) {
    __shared__ unsigned short sF[2250];
    __shared__ unsigned short sB[8704];

    const int tid = threadIdx.x;
    const int bid = blockIdx.x;
    const int s = bid & 63, cig = bid >> 6;
    const int t3 = s & 3, t2 = (s >> 2) & 3, t1 = s >> 4;
    const int bo1 = 2 * t1, bo2 = 2 * t2, bo3 = 2 * t3;   // bo4 = 0

    // staging: hpad zero-padded -> no masks; direct u32 loads
    int offs[5], swb[5];
#pragma unroll
    for (int r = 0; r < 5; ++r) {
        int u = tid + 256 * r;
        if (u >= 1125) u = 0;
        int p = u % 9, q = u / 9;
        int i3 = q % 5; q /= 5;
        int i2 = q % 5; int i1 = q / 5;
        offs[r] = (2 * bo1 + i1) * 5832 + (2 * bo2 + i2) * 324 + (2 * bo3 + i3) * 18 + 2 * p;
        swb[r] = 2 * (((i1 * 5 + i2) * 5 + i3) * 18 + 2 * p);
    }

    const int sp = tid & 63, g0 = tid >> 6;
    const int o4l = sp & 7, o3l = (sp >> 3) & 1, o2l = (sp >> 4) & 1, o1l = sp >> 5;
    const int fpbase = o1l * 900 + o2l * 180 + o3l * 36 + o4l * 2;
    const int wkey = ((sp >> 3) & 7) << 4;
    const int wbase = sp * 272;

    int rba[4], rbb[4], wba[4];
#pragma unroll
    for (int i = 0; i < 4; ++i) {
        int gp = g0 + 4 * i;
        int ga = 2 * gp, gb = 2 * gp + 1;
        if (ga > 26) ga = 26;
        if (gb > 26) gb = 26;
        rba[i] = 2 * (fpbase + (ga / 9) * 450 + ((ga / 3) % 3) * 90 + (ga % 3) * 18);
        rbb[i] = 2 * (fpbase + (gb / 9) * 450 + ((gb / 3) % 3) * 90 + (gb % 3) * 18);
        wba[i] = (wbase + gp * 16) ^ wkey;
    }
    const bool zlast = (g0 >= 2);

    const int lane = tid & 63, wv = tid >> 6;
    const int n16 = lane & 15, hi = lane >> 4, n8 = n16 >> 3;
    const int bbase = n16 * 272 + hi * 16;

    unsigned fvp[5];
    {
        const unsigned short* hc = hpad + (size_t)(cig * 4) * 104976;
#pragma unroll
        for (int r = 0; r < 5; ++r) fvp[r] = *(const unsigned*)(hc + offs[r]);
    }

    f32x4 acc = (f32x4){0.f, 0.f, 0.f, 0.f};

    for (int s8 = 0; s8 < 4; ++s8) {
        const int ci = cig * 4 + s8;
#pragma unroll
        for (int r = 0; r < 4; ++r) *(unsigned*)((char*)sF + swb[r]) = fvp[r];
        if (tid < 101) *(unsigned*)((char*)sF + swb[4]) = fvp[4];
        lgkm_barrier();   // B1

        const unsigned short* aw = w2p + (size_t)(ci * 16 + n16) * 136 + hi * 8;
        short8 a0 = *(const short8*)(aw);
        short8 a1 = *(const short8*)(aw + 32);
        short8 a2 = *(const short8*)(aw + 64);
        short8 a3 = *(const short8*)(aw + 96);

        unsigned nfp[5];
        if (s8 < 3) {
            const unsigned short* hc = hpad + (size_t)(ci + 1) * 104976;
#pragma unroll
            for (int r = 0; r < 5; ++r) nfp[r] = *(const unsigned*)(hc + offs[r]);
        }

#pragma unroll
        for (int i = 0; i < 4; ++i) {
            if (i == 3 && zlast) {
                *(uint4v*)((char*)sB + wba[3]) = (uint4v){0, 0, 0, 0};
            } else {
                unsigned w0  = *(const unsigned*)((const char*)sF + rba[i]);
                unsigned w1_ = *(const unsigned*)((const char*)sF + rba[i] + 4);
                unsigned w2_ = *(const unsigned*)((const char*)sF + rbb[i]);
                unsigned w3_ = *(const unsigned*)((const char*)sF + rbb[i] + 4);
                *(uint4v*)((char*)sB + wba[i]) = (uint4v){w0, w1_, w2_, w3_};
            }
        }
        lgkm_barrier();   // B2

        {
            const int tb = bbase + wv * 4352;
            const int xv = (((2 * wv) & 7) + n8) << 4;
            short8 b0  = *(const short8*)((const char*)sB + ((tb + 0)   ^ xv));
            short8 b1f = *(const short8*)((const char*)sB + ((tb + 64)  ^ xv));
            short8 b2f = *(const short8*)((const char*)sB + ((tb + 128) ^ xv));
            short8 b3f = *(const short8*)((const char*)sB + ((tb + 192) ^ xv));
            acc = __builtin_amdgcn_mfma_f32_16x16x32_bf16(a0, b0,  acc, 0, 0, 0);
            acc = __builtin_amdgcn_mfma_f32_16x16x32_bf16(a1, b1f, acc, 0, 0, 0);
            acc = __builtin_amdgcn_mfma_f32_16x16x32_bf16(a2, b2f, acc, 0, 0, 0);
            acc = __builtin_amdgcn_mfma_f32_16x16x32_bf16(a3, b3f, acc, 0, 0, 0);
        }

        if (s8 < 3) {
#pragma unroll
            for (int r = 0; r < 5; ++r) fvp[r] = nfp[r];
        }
    }

    {
        int spl = 16 * wv + n16;
        int e4 = spl & 7, e3 = (spl >> 3) & 1, e2 = (spl >> 4) & 1, e1 = spl >> 5;
        int o1 = bo1 + e1, o2 = bo2 + e2, o3 = bo3 + e3, o4 = e4;
#pragma unroll
        for (int r = 0; r < 4; ++r) {
            int co = 4 * hi + r;
            atomicAdd(&out[(size_t)co * 4096 + o1 * 512 + o2 * 64 + o3 * 8 + o4], acc[r]);
        }
    }
}

// ---------------------------------------------------------------------------
extern "C" void kernel_launch(void* const* d_in, const int* in_sizes, int n_in,
                              void* d_out, int out_size, void* d_ws, size_t ws_size,
                              hipStream_t stream) {
    const float* x  = (const float*)d_in[0];
    const float* w1 = (const float*)d_in[1];
    const float* b1 = (const float*)d_in[2];
    const float* w2 = (const float*)d_in[3];
    const float* b2 = (const float*)d_in[4];
    float* out = (float*)d_out;

    unsigned short* hpad = (unsigned short*)d_ws;        // 64*18^4 = 6,718,464 bf16
    unsigned short* w1p  = hpad + 6718464;               // 139,264 bf16
    unsigned short* w2p  = w1p + 139264;                 // 139,264 bf16

    setup_kernel<<<4096, 256, 0, stream>>>(w1, w2, b2, w1p, w2p, (uint4v*)hpad, out);
    conv1_mfma<<<512, 256, 0, stream>>>(x, w1p, b1, hpad);
    conv2_mfma<<<1024, 256, 0, stream>>>(hpad, w2p, out);
}

// Round 8
// 86.628 us; speedup vs baseline: 1.6820x; 1.6028x over previous
//
#include <hip/hip_runtime.h>
#include <hip/hip_bf16.h>
#include <math.h>

// ---------------------------------------------------------------------------
// MLPConv4d via bf16 MFMA implicit GEMM (v6: whole-footprint LDS, barrier-free
// K-loop, B-fragments read directly from footprint — no im2col expand).
// conv1: x[16][32^4] fp32 -> hpad[64][18^4] bf16 (GELU'd, zero shell)
// conv2: hpad -> out[16][8^4] fp32 (split-K atomics onto bias-init'd out)
// K layout: k' = grp*4 + k4; grp=(k1*3+k2)*3+k3 < 27. k4=3 slots and k'>=108
// are ZERO in prepacked weights => junk B-reads there are harmless (finite).
// Footprint slab per ci: [i1 5][i2 5][i3 5][i4 18] bf16 = 2250 shorts (4500 B).
// B-frag(sp, ks): lane(n16,hi) reads groups g = 8ks+2hi+{0,1} (clamp 26):
//   2x b32 at slab + 2*(fpbase(sp)+koff(g)) + {0,4}  — all 4B aligned.
// ---------------------------------------------------------------------------

typedef __attribute__((ext_vector_type(8))) short short8;
typedef __attribute__((ext_vector_type(4))) float f32x4;
typedef __attribute__((ext_vector_type(4))) unsigned int uint4v;

__device__ __forceinline__ unsigned short f2bf(float v) {
    __hip_bfloat16 b = __float2bfloat16(v);
    return *(unsigned short*)&b;
}

// ---- fused setup: prepack w1/w2 (zero-padded k'), bias-init out, zero hpad -
__global__ void setup_kernel(const float* __restrict__ w1, const float* __restrict__ w2,
                             const float* __restrict__ b2,
                             unsigned short* __restrict__ w1p, unsigned short* __restrict__ w2p,
                             uint4v* __restrict__ hz, float* __restrict__ out) {
    int b = blockIdx.x, tid = threadIdx.x;
    if (b < 544) {                       // w1p: 16*64*136 = 139264 = 544*256
        int i = b * 256 + tid;
        int kp = i % 136, co = (i / 136) & 63, ci = i / 8704;
        float v = 0.f;
        if (kp < 108 && (kp & 3) < 3) v = w1[(co * 16 + ci) * 81 + (kp >> 2) * 3 + (kp & 3)];
        w1p[i] = f2bf(v);
    } else if (b < 1088) {               // w2p: 64*16*136 = 139264
        int i = (b - 544) * 256 + tid;
        int kp = i % 136, co = (i / 136) & 15, ci = i / 2176;
        float v = 0.f;
        if (kp < 108 && (kp & 3) < 3) v = w2[(co * 64 + ci) * 81 + (kp >> 2) * 3 + (kp & 3)];
        w2p[i] = f2bf(v);
    } else if (b < 1344) {               // out = bias: 65536
        int i = (b - 1088) * 256 + tid;
        out[i] = b2[i >> 12];
    } else {                             // zero hpad: 839808 uint4
        int i = (b - 1344) * 256 + tid;  // 2752*256 = 704512
        hz[i] = (uint4v){0, 0, 0, 0};
        int j = i + 704512;
        if (j < 839808) hz[j] = (uint4v){0, 0, 0, 0};
    }
}

// ---------------- conv1: barrier-free K-loop --------------------------------
// Block: sp 64 = (o1,o2,o3,o4)=(2,2,2,8), 64 co. Grid 1024, 256 thr, 70.3 KB.
// Wave wv: sp-tiles 2(wv>>1)+{0,1}, co-tiles 2(wv&1)+{0,1}; 16 MFMA/ci.
__global__ __launch_bounds__(256) void conv1_mfma(
        const float* __restrict__ x, const unsigned short* __restrict__ w1p,
        const float* __restrict__ b1, unsigned short* __restrict__ hpad) {
    __shared__ unsigned short sX[36000];   // [ci 16][2250] = 72000 B

    const int tid = threadIdx.x;
    const int bid = blockIdx.x;
    const int t4 = bid & 1, t3 = (bid >> 1) & 7, t2 = (bid >> 4) & 7, t1 = bid >> 7;
    const int bo1 = 2 * t1, bo2 = 2 * t2, bo3 = 2 * t3, bo4 = 8 * t4;
    const int g1b = 2 * bo1 - 1, g2b = 2 * bo2 - 1, g3b = 2 * bo3 - 1, g4b = 2 * bo4 - 1;

    // ---- staging slots: 1125 u32-units/ci (2 i4 elems), u = tid + 256r, r<5
    int offs[5], swb[5];
    unsigned mka = 0, mkb = 0;
#pragma unroll
    for (int r = 0; r < 5; ++r) {
        int u = tid + 256 * r;
        bool uok = u < 1125;
        int uu = uok ? u : 0;
        int p = uu % 9, q = uu / 9;
        int i3 = q % 5; q /= 5;
        int i2 = q % 5; int i1 = q / 5;
        int g1 = g1b + i1, g2 = g2b + i2, g3 = g3b + i3;
        bool ok123 = uok & ((unsigned)g1 < 32u) & ((unsigned)g2 < 32u) & ((unsigned)g3 < 32u);
        int g4a = g4b + 2 * p;
        offs[r] = ((g1 * 32 + g2) * 32 + g3) * 32 + g4a;
        if (ok123 && (unsigned)g4a < 32u) mka |= 1u << r;
        if (ok123 && (unsigned)(g4a + 1) < 32u) mkb |= 1u << r;
        swb[r] = 2 * (((i1 * 5 + i2) * 5 + i3) * 18 + 2 * p);
    }

    // ---- stage all 16 ci (1-deep pipelined, masked-at-issue) ----
    {
        float fa[5], fb[5], na[5], nb[5];
#pragma unroll
        for (int r = 0; r < 5; ++r) {
            float va = 0.f, vb = 0.f;
            if ((mka >> r) & 1) va = x[offs[r]];
            if ((mkb >> r) & 1) vb = x[offs[r] + 1];
            fa[r] = va; fb[r] = vb;
        }
        for (int ci = 0; ci < 16; ++ci) {
            if (ci < 15) {
                const float* xc = x + (size_t)(ci + 1) * 1048576;
#pragma unroll
                for (int r = 0; r < 5; ++r) {
                    float va = 0.f, vb = 0.f;
                    if ((mka >> r) & 1) va = xc[offs[r]];
                    if ((mkb >> r) & 1) vb = xc[offs[r] + 1];
                    na[r] = va; nb[r] = vb;
                }
            }
            char* slab = (char*)sX + ci * 4500;
#pragma unroll
            for (int r = 0; r < 4; ++r)
                *(unsigned*)(slab + swb[r]) =
                    (unsigned)f2bf(fa[r]) | ((unsigned)f2bf(fb[r]) << 16);
            if (tid < 101)
                *(unsigned*)(slab + swb[4]) =
                    (unsigned)f2bf(fa[4]) | ((unsigned)f2bf(fb[4]) << 16);
            if (ci < 15) {
#pragma unroll
                for (int r = 0; r < 5; ++r) { fa[r] = na[r]; fb[r] = nb[r]; }
            }
        }
    }
    __syncthreads();   // the ONLY barrier

    // ---- K-loop constants ----
    const int lane = tid & 63, wv = tid >> 6;
    const int n16 = lane & 15, hi = lane >> 4;
    const int ct0 = 2 * (wv & 1);
    const int st0 = 2 * (wv >> 1);

    int fpb[2];
#pragma unroll
    for (int tt = 0; tt < 2; ++tt) {
        int sp = (st0 + tt) * 16 + n16;
        int o4l = sp & 7, o3l = (sp >> 3) & 1, o2l = (sp >> 4) & 1, o1l = sp >> 5;
        fpb[tt] = 2 * (900 * o1l + 180 * o2l + 36 * o3l + 2 * o4l);
    }
    int kof[4][2];
#pragma unroll
    for (int ks = 0; ks < 4; ++ks)
#pragma unroll
    for (int j = 0; j < 2; ++j) {
        int g = 8 * ks + 2 * hi + j;
        if (g > 26) g = 26;                   // zero-weight region
        int k1 = g / 9, k2 = (g / 3) % 3, k3 = g % 3;
        kof[ks][j] = 2 * (450 * k1 + 90 * k2 + 18 * k3);
    }

    auto loadA = [&](int ci, short8 (&Ac)[8]) {
        const unsigned short* aw0 = w1p + (size_t)(ci * 64 + 16 * ct0 + n16) * 136 + hi * 8;
#pragma unroll
        for (int k = 0; k < 4; ++k) Ac[k] = *(const short8*)(aw0 + 32 * k);
        const unsigned short* aw1 = aw0 + 16 * 136;
#pragma unroll
        for (int k = 0; k < 4; ++k) Ac[4 + k] = *(const short8*)(aw1 + 32 * k);
    };

    f32x4 acc[2][2];
#pragma unroll
    for (int c = 0; c < 2; ++c)
#pragma unroll
    for (int t = 0; t < 2; ++t) acc[c][t] = (f32x4){0.f, 0.f, 0.f, 0.f};

    short8 A0[8], A1[8];
    loadA(0, A0);
    loadA(1, A1);

    auto kbody = [&](int ci, short8 (&Ac)[8]) {
        const char* sx = (const char*)sX + ci * 4500;
        short8 fr[2][4];
#pragma unroll
        for (int tt = 0; tt < 2; ++tt) {
            const char* base = sx + fpb[tt];
#pragma unroll
            for (int ks = 0; ks < 4; ++ks) {
                unsigned r0 = *(const unsigned*)(base + kof[ks][0]);
                unsigned r1 = *(const unsigned*)(base + kof[ks][0] + 4);
                unsigned r2 = *(const unsigned*)(base + kof[ks][1]);
                unsigned r3 = *(const unsigned*)(base + kof[ks][1] + 4);
                uint4v tmp = (uint4v){r0, r1, r2, r3};
                fr[tt][ks] = *(short8*)&tmp;
            }
        }
#pragma unroll
        for (int tt = 0; tt < 2; ++tt)
#pragma unroll
        for (int ks = 0; ks < 4; ++ks) {
            acc[0][tt] = __builtin_amdgcn_mfma_f32_16x16x32_bf16(Ac[ks],     fr[tt][ks], acc[0][tt], 0, 0, 0);
            acc[1][tt] = __builtin_amdgcn_mfma_f32_16x16x32_bf16(Ac[4 + ks], fr[tt][ks], acc[1][tt], 0, 0, 0);
        }
        if (ci < 14) loadA(ci + 2, Ac);
    };

    for (int cc = 0; cc < 16; cc += 2) {
        kbody(cc, A0);
        kbody(cc + 1, A1);
    }

    // ---- epilogue: bias + exact GELU + bf16 store ----
#pragma unroll
    for (int c = 0; c < 2; ++c) {
#pragma unroll
        for (int tt = 0; tt < 2; ++tt) {
            int spl = 16 * (st0 + tt) + n16;
            int e4 = spl & 7, e3 = (spl >> 3) & 1, e2 = (spl >> 4) & 1, e1 = spl >> 5;
            size_t base = (size_t)(bo1 + e1 + 1) * 5832 + (bo2 + e2 + 1) * 324 +
                          (bo3 + e3 + 1) * 18 + (bo4 + e4 + 1);
#pragma unroll
            for (int r = 0; r < 4; ++r) {
                int co = 16 * (ct0 + c) + 4 * hi + r;
                float v = acc[c][tt][r] + b1[co];
                v = 0.5f * v * (1.f + erff(v * 0.70710678118654752f));
                hpad[(size_t)co * 104976 + base] = f2bf(v);
            }
        }
    }
}

// ---------------- conv2: barrier-free K-loop, split-K atomics ---------------
// Block: sp 64 = (2,2,2,8) over out 8^4 (64 tiles) x 8 ci-groups (8 ci each).
// Grid 512, 36000 B LDS -> 4 blocks/CU. Wave wv: sp-tile wv, all 16 co.
__global__ __launch_bounds__(256) void conv2_mfma(
        const unsigned short* __restrict__ hpad, const unsigned short* __restrict__ w2p,
        float* __restrict__ out) {
    __shared__ unsigned short sX[18000];   // [ci 8][2250] = 36000 B

    const int tid = threadIdx.x;
    const int bid = blockIdx.x;
    const int s = bid & 63, cig = bid >> 6;
    const int t3 = s & 3, t2 = (s >> 2) & 3, t1 = s >> 4;
    const int bo1 = 2 * t1, bo2 = 2 * t2, bo3 = 2 * t3;   // bo4 = 0

    // staging: hpad zero-padded -> no masks, direct u32 copies
    int offs[5], swb[5];
#pragma unroll
    for (int r = 0; r < 5; ++r) {
        int u = tid + 256 * r;
        if (u >= 1125) u = 0;
        int p = u % 9, q = u / 9;
        int i3 = q % 5; q /= 5;
        int i2 = q % 5; int i1 = q / 5;
        offs[r] = (2 * bo1 + i1) * 5832 + (2 * bo2 + i2) * 324 + (2 * bo3 + i3) * 18 + 2 * p;
        swb[r] = 2 * (((i1 * 5 + i2) * 5 + i3) * 18 + 2 * p);
    }

    // ---- stage 8 ci (1-deep pipelined) ----
    {
        unsigned fa[5], na[5];
        const unsigned short* h0 = hpad + (size_t)(cig * 8) * 104976;
#pragma unroll
        for (int r = 0; r < 5; ++r) fa[r] = *(const unsigned*)(h0 + offs[r]);
        for (int s8 = 0; s8 < 8; ++s8) {
            if (s8 < 7) {
                const unsigned short* hc = hpad + (size_t)(cig * 8 + s8 + 1) * 104976;
#pragma unroll
                for (int r = 0; r < 5; ++r) na[r] = *(const unsigned*)(hc + offs[r]);
            }
            char* slab = (char*)sX + s8 * 4500;
#pragma unroll
            for (int r = 0; r < 4; ++r) *(unsigned*)(slab + swb[r]) = fa[r];
            if (tid < 101) *(unsigned*)(slab + swb[4]) = fa[4];
            if (s8 < 7) {
#pragma unroll
                for (int r = 0; r < 5; ++r) fa[r] = na[r];
            }
        }
    }
    __syncthreads();   // the ONLY barrier

    const int lane = tid & 63, wv = tid >> 6;
    const int n16 = lane & 15, hi = lane >> 4;

    int fpb;
    {
        int sp = wv * 16 + n16;
        int o4l = sp & 7, o3l = (sp >> 3) & 1, o2l = (sp >> 4) & 1, o1l = sp >> 5;
        fpb = 2 * (900 * o1l + 180 * o2l + 36 * o3l + 2 * o4l);
    }
    int kof[4][2];
#pragma unroll
    for (int ks = 0; ks < 4; ++ks)
#pragma unroll
    for (int j = 0; j < 2; ++j) {
        int g = 8 * ks + 2 * hi + j;
        if (g > 26) g = 26;
        int k1 = g / 9, k2 = (g / 3) % 3, k3 = g % 3;
        kof[ks][j] = 2 * (450 * k1 + 90 * k2 + 18 * k3);
    }

    auto loadA = [&](int s8, short8 (&Ac)[4]) {
        const unsigned short* aw = w2p + (size_t)((cig * 8 + s8) * 16 + n16) * 136 + hi * 8;
#pragma unroll
        for (int k = 0; k < 4; ++k) Ac[k] = *(const short8*)(aw + 32 * k);
    };

    f32x4 acc = (f32x4){0.f, 0.f, 0.f, 0.f};
    short8 A0[4], A1[4];
    loadA(0, A0);
    loadA(1, A1);

    auto kbody = [&](int s8, short8 (&Ac)[4]) {
        const char* base = (const char*)sX + s8 * 4500 + fpb;
        short8 fr[4];
#pragma unroll
        for (int ks = 0; ks < 4; ++ks) {
            unsigned r0 = *(const unsigned*)(base + kof[ks][0]);
            unsigned r1 = *(const unsigned*)(base + kof[ks][0] + 4);
            unsigned r2 = *(const unsigned*)(base + kof[ks][1]);
            unsigned r3 = *(const unsigned*)(base + kof[ks][1] + 4);
            uint4v tmp = (uint4v){r0, r1, r2, r3};
            fr[ks] = *(short8*)&tmp;
        }
#pragma unroll
        for (int ks = 0; ks < 4; ++ks)
            acc = __builtin_amdgcn_mfma_f32_16x16x32_bf16(Ac[ks], fr[ks], acc, 0, 0, 0);
        if (s8 < 6) loadA(s8 + 2, Ac);
    };

    for (int cc = 0; cc < 8; cc += 2) {
        kbody(cc, A0);
        kbody(cc + 1, A1);
    }

    {
        int spl = 16 * wv + n16;
        int e4 = spl & 7, e3 = (spl >> 3) & 1, e2 = (spl >> 4) & 1, e1 = spl >> 5;
        int o1 = bo1 + e1, o2 = bo2 + e2, o3 = bo3 + e3, o4 = e4;
#pragma unroll
        for (int r = 0; r < 4; ++r) {
            int co = 4 * hi + r;
            atomicAdd(&out[(size_t)co * 4096 + o1 * 512 + o2 * 64 + o3 * 8 + o4], acc[r]);
        }
    }
}

// ---------------------------------------------------------------------------
extern "C" void kernel_launch(void* const* d_in, const int* in_sizes, int n_in,
                              void* d_out, int out_size, void* d_ws, size_t ws_size,
                              hipStream_t stream) {
    const float* x  = (const float*)d_in[0];
    const float* w1 = (const float*)d_in[1];
    const float* b1 = (const float*)d_in[2];
    const float* w2 = (const float*)d_in[3];
    const float* b2 = (const float*)d_in[4];
    float* out = (float*)d_out;

    unsigned short* hpad = (unsigned short*)d_ws;        // 64*18^4 = 6,718,464 bf16
    unsigned short* w1p  = hpad + 6718464;               // 139,264 bf16
    unsigned short* w2p  = w1p + 139264;                 // 139,264 bf16

    setup_kernel<<<4096, 256, 0, stream>>>(w1, w2, b2, w1p, w2p, (uint4v*)hpad, out);
    conv1_mfma<<<1024, 256, 0, stream>>>(x, w1p, b1, hpad);
    conv2_mfma<<<512, 256, 0, stream>>>(hpad, w2p, out);
}